// Round 8
// baseline (496.832 us; speedup 1.0000x reference)
//
#include <hip/hip_runtime.h>
#include <hip/hip_bf16.h>

#define NN   100000
#define NE   1600000
#define NBK  196      // ceil(NN/512) buckets
#define BSH  9        // 512 nodes per bucket
#define EPB  8192     // edges per scatter block
#define CAP  9216     // max edges per bucket

typedef __attribute__((ext_vector_type(8))) short short8;
typedef __attribute__((ext_vector_type(4))) float f32x4;

__device__ __forceinline__ ushort f2bf(float f) {
    union { float f; uint u; } v; v.f = f;
    uint u = v.u;
    return (ushort)((u + 0x7FFFu + ((u >> 16) & 1u)) >> 16);
}
__device__ __forceinline__ float bf2f(uint b) {
    union { uint u; float f; } v; v.u = b << 16;
    return v.f;
}
// XOR-swizzle for 512B-stride LDS rows (guide G4)
__device__ __forceinline__ int swz(int off) { return off ^ (((off >> 9) & 7) << 4); }

// ---------------- bucket histogram ----------------
__global__ __launch_bounds__(256) void bucket_hist(const int* __restrict__ tgt,
                                                   int* __restrict__ bcnt) {
    __shared__ int lh[NBK];
    int tid = threadIdx.x;
    for (int i = tid; i < NBK; i += 256) lh[i] = 0;
    __syncthreads();
    int base4 = blockIdx.x * (EPB / 4);
#pragma unroll
    for (int k = 0; k < 8; ++k) {
        int i4 = base4 + k * 256 + tid;
        if (i4 < NE / 4) {
            int4 t = ((const int4*)tgt)[i4];
            atomicAdd(&lh[t.x >> BSH], 1);
            atomicAdd(&lh[t.y >> BSH], 1);
            atomicAdd(&lh[t.z >> BSH], 1);
            atomicAdd(&lh[t.w >> BSH], 1);
        }
    }
    __syncthreads();
    for (int i = tid; i < NBK; i += 256)
        if (lh[i]) atomicAdd(&bcnt[i], lh[i]);
}

// ---------------- bucket scan ----------------
__global__ __launch_bounds__(256) void bucket_scan(const int* __restrict__ bcnt,
                                                   int* __restrict__ bbase,
                                                   int* __restrict__ bcursor,
                                                   int* __restrict__ rowstart) {
    int t = threadIdx.x;
    int v = (t < NBK) ? bcnt[t] : 0;
    int lane = t & 63, wid = t >> 6;
    int inc = v;
#pragma unroll
    for (int off = 1; off < 64; off <<= 1) {
        int u = __shfl_up(inc, off);
        if (lane >= off) inc += u;
    }
    __shared__ int ws[4];
    if (lane == 63) ws[wid] = inc;
    __syncthreads();
    int woff = 0;
    for (int w = 0; w < wid; ++w) woff += ws[w];
    int ex = woff + inc - v;
    if (t < NBK) { bbase[t] = ex; bcursor[t] = ex; }
    if (t == NBK) bbase[NBK] = ex;
    if (t == 255) rowstart[NN] = NE;
}

// ------- bucket scatter -------
__global__ __launch_bounds__(256) void bucket_scatter(const int* __restrict__ src,
                                                      const int* __restrict__ tgt,
                                                      int* __restrict__ bcursor,
                                                      uint* __restrict__ brec) {
    __shared__ int lh[NBK + 1];
    __shared__ int lcur[NBK];
    __shared__ int lbase[NBK];
    __shared__ uint lrec[EPB];
    __shared__ int ws[4];
    int tid = threadIdx.x;
    for (int i = tid; i < NBK; i += 256) lh[i] = 0;
    __syncthreads();
    int base4 = blockIdx.x * (EPB / 4);
#pragma unroll
    for (int k = 0; k < 8; ++k) {
        int i4 = base4 + k * 256 + tid;
        if (i4 < NE / 4) {
            int4 t = ((const int4*)tgt)[i4];
            atomicAdd(&lh[t.x >> BSH], 1);
            atomicAdd(&lh[t.y >> BSH], 1);
            atomicAdd(&lh[t.z >> BSH], 1);
            atomicAdd(&lh[t.w >> BSH], 1);
        }
    }
    __syncthreads();
    int v = (tid < NBK) ? lh[tid] : 0;
    int lane = tid & 63, wid = tid >> 6;
    int inc = v;
#pragma unroll
    for (int off = 1; off < 64; off <<= 1) {
        int u = __shfl_up(inc, off);
        if (lane >= off) inc += u;
    }
    if (lane == 63) ws[wid] = inc;
    __syncthreads();
    int woff = 0;
    for (int w = 0; w < wid; ++w) woff += ws[w];
    int ex = woff + inc - v;
    int nval = min(EPB, NE - blockIdx.x * EPB);
    if (tid < NBK) {
        lh[tid] = ex;
        lcur[tid] = ex;
        lbase[tid] = v ? atomicAdd(&bcursor[tid], v) : 0;
    }
    if (tid == 0) lh[NBK] = nval;
    __syncthreads();
#pragma unroll
    for (int k = 0; k < 8; ++k) {
        int i4 = base4 + k * 256 + tid;
        if (i4 < NE / 4) {
            int4 t = ((const int4*)tgt)[i4];
            int4 s = ((const int4*)src)[i4];
            int p;
            p = atomicAdd(&lcur[t.x >> BSH], 1); lrec[p] = ((uint)s.x << BSH) | (uint)(t.x & 511);
            p = atomicAdd(&lcur[t.y >> BSH], 1); lrec[p] = ((uint)s.y << BSH) | (uint)(t.y & 511);
            p = atomicAdd(&lcur[t.z >> BSH], 1); lrec[p] = ((uint)s.z << BSH) | (uint)(t.z & 511);
            p = atomicAdd(&lcur[t.w >> BSH], 1); lrec[p] = ((uint)s.w << BSH) | (uint)(t.w & 511);
        }
    }
    __syncthreads();
    for (int i = tid; i < nval; i += 256) {
        int lo = 0, hi = NBK;
        while (hi - lo > 1) { int mid = (lo + hi) >> 1; if (lh[mid] <= i) lo = mid; else hi = mid; }
        brec[lbase[lo] + (i - lh[lo])] = lrec[i];
    }
}

// ------- bucket -> CSR -------
__global__ __launch_bounds__(256) void bucket_to_csr(const uint* __restrict__ brec,
                                                     const int* __restrict__ bbase,
                                                     int* __restrict__ rowstart,
                                                     int* __restrict__ sortedSrc) {
    __shared__ int cnt[512];
    __shared__ int cur[512];
    __shared__ int srt[CAP];
    __shared__ int ws[4];
    int b = blockIdx.x;
    int beg = bbase[b], end = bbase[b + 1];
    int len = end - beg;
    int n0 = b << BSH;
    int ncnt = min(512, NN - n0);
    int tid = threadIdx.x;
    cnt[tid] = 0; cnt[tid + 256] = 0;
    __syncthreads();
    for (int i = beg + tid; i < end; i += 256)
        atomicAdd(&cnt[brec[i] & 511u], 1);
    __syncthreads();
    int c0 = cnt[2 * tid], c1 = cnt[2 * tid + 1];
    int s = c0 + c1;
    int lane = tid & 63, wid = tid >> 6;
    int inc = s;
#pragma unroll
    for (int off = 1; off < 64; off <<= 1) {
        int u = __shfl_up(inc, off);
        if (lane >= off) inc += u;
    }
    if (lane == 63) ws[wid] = inc;
    __syncthreads();
    int woff = 0;
    for (int w = 0; w < wid; ++w) woff += ws[w];
    int ex = woff + inc - s;
    cur[2 * tid] = ex; cur[2 * tid + 1] = ex + c0;
    if (2 * tid < ncnt)     rowstart[n0 + 2 * tid]     = beg + ex;
    if (2 * tid + 1 < ncnt) rowstart[n0 + 2 * tid + 1] = beg + ex + c0;
    __syncthreads();
    if (len <= CAP) {
        for (int i = beg + tid; i < end; i += 256) {
            uint r = brec[i];
            int p = atomicAdd(&cur[r & 511u], 1);
            srt[p] = (int)(r >> BSH);
        }
        __syncthreads();
        for (int i = tid; i < len; i += 256)
            sortedSrc[beg + i] = srt[i];
    } else {
        for (int i = beg + tid; i < end; i += 256) {
            uint r = brec[i];
            int p = atomicAdd(&cur[r & 511u], 1);
            sortedSrc[beg + p] = (int)(r >> BSH);
        }
    }
}

// ---------------- weight prep ----------------
__global__ __launch_bounds__(256) void prep_w(const float* __restrict__ W1l,
                                              const float* __restrict__ W1r,
                                              const float* __restrict__ Wlin,
                                              const float* __restrict__ W2l,
                                              const float* __restrict__ W2r,
                                              ushort* __restrict__ Wcat1,
                                              ushort* __restrict__ Wlinb,
                                              ushort* __restrict__ Wcat2) {
    int i = blockIdx.x * 256 + threadIdx.x;
    if (i < 65536) {
        int o = i >> 8, k = i & 255;
        float v = (k < 128) ? W1l[o * 128 + k] : W1r[o * 128 + k - 128];
        Wcat1[i] = f2bf(v);
    } else if (i < 98304) {
        int j = i - 65536;
        Wlinb[j] = f2bf(Wlin[j]);
    } else {
        int j = i - 98304;
        int o = j >> 8, k = j & 255;
        float v = (k < 128) ? W2l[o * 128 + k] : W2r[o * 128 + k - 128];
        Wcat2[j] = f2bf(v);
    }
}

// ---------------- x fp32 -> bf16 ----------------
__global__ __launch_bounds__(256) void xcvt(const float* __restrict__ x,
                                            ushort* __restrict__ xbf) {
    int i = blockIdx.x * 256 + threadIdx.x;
    float4 v = ((const float4*)x)[i];
    ushort4 p;
    p.x = f2bf(v.x); p.y = f2bf(v.y); p.z = f2bf(v.z); p.w = f2bf(v.w);
    ((ushort4*)xbf)[i] = p;
}

// --- fused gather: wave handles 16 nodes, quarter-wave/edge, unroll-4;
//     writes bf16 mean rows into As cols 0..127 (swizzled) ---
__device__ __forceinline__ void gather_into_As(const ushort* __restrict__ xin,
                                               const int* __restrict__ rowstart,
                                               const int* __restrict__ sortedSrc,
                                               char* As, int m0, int tid) {
    int lane = tid & 63, wave = tid >> 6;
    int q = lane >> 4, l = lane & 15;
#define ACCA(v) { a0 += bf2f(v.x & 0xffffu); a1 += bf2f(v.x >> 16); \
                  a2 += bf2f(v.y & 0xffffu); a3 += bf2f(v.y >> 16); \
                  a4 += bf2f(v.z & 0xffffu); a5 += bf2f(v.z >> 16); \
                  a6 += bf2f(v.w & 0xffffu); a7 += bf2f(v.w >> 16); }
#define ACCC(v) { c0 += bf2f(v.x & 0xffffu); c1 += bf2f(v.x >> 16); \
                  c2 += bf2f(v.y & 0xffffu); c3 += bf2f(v.y >> 16); \
                  c4 += bf2f(v.z & 0xffffu); c5 += bf2f(v.z >> 16); \
                  c6 += bf2f(v.w & 0xffffu); c7 += bf2f(v.w >> 16); }
    for (int b = 0; b < 16; ++b) {
        int rl = wave * 16 + b;
        int node = m0 + rl;
        float a0=0.f,a1=0.f,a2=0.f,a3=0.f,a4=0.f,a5=0.f,a6=0.f,a7=0.f;
        float c0=0.f,c1=0.f,c2=0.f,c3=0.f,c4=0.f,c5=0.f,c6=0.f,c7=0.f;
        int deg = 0;
        if (node < NN) {
            int beg = rowstart[node], end = rowstart[node + 1];
            deg = end - beg;
            int i = beg + q;
            for (; i + 12 < end; i += 16) {
                int s0 = sortedSrc[i],      s1 = sortedSrc[i + 4];
                int s2 = sortedSrc[i + 8],  s3 = sortedSrc[i + 12];
                uint4 v0 = *(const uint4*)&xin[(size_t)s0 * 128 + l * 8];
                uint4 v1 = *(const uint4*)&xin[(size_t)s1 * 128 + l * 8];
                uint4 v2 = *(const uint4*)&xin[(size_t)s2 * 128 + l * 8];
                uint4 v3 = *(const uint4*)&xin[(size_t)s3 * 128 + l * 8];
                ACCA(v0) ACCC(v1) ACCA(v2) ACCC(v3)
            }
            for (; i < end; i += 4) {
                int s0 = sortedSrc[i];
                uint4 v0 = *(const uint4*)&xin[(size_t)s0 * 128 + l * 8];
                ACCA(v0)
            }
        }
        a0 += c0; a1 += c1; a2 += c2; a3 += c3;
        a4 += c4; a5 += c5; a6 += c6; a7 += c7;
#define CMB(a) a += __shfl_xor(a, 32); a += __shfl_xor(a, 16);
        CMB(a0) CMB(a1) CMB(a2) CMB(a3) CMB(a4) CMB(a5) CMB(a6) CMB(a7)
#undef CMB
        if (lane < 16) {
            float id = 1.0f / fmaxf((float)deg, 1.0f);
            ushort p[8];
            p[0] = f2bf(a0 * id); p[1] = f2bf(a1 * id);
            p[2] = f2bf(a2 * id); p[3] = f2bf(a3 * id);
            p[4] = f2bf(a4 * id); p[5] = f2bf(a5 * id);
            p[6] = f2bf(a6 * id); p[7] = f2bf(a7 * id);
            *(uint4*)(As + swz(rl * 512 + l * 16)) = *(uint4*)p;
        }
    }
#undef ACCA
#undef ACCC
}

// --- conv1 + linear fused, with in-kernel gather ---
__global__ __launch_bounds__(256) void conv1lin_g(const ushort* __restrict__ xbf,
                                                  const int* __restrict__ rowstart,
                                                  const int* __restrict__ sortedSrc,
                                                  const ushort* __restrict__ Wcat,
                                                  const float* __restrict__ bias1,
                                                  const ushort* __restrict__ Wlin,
                                                  const float* __restrict__ blin,
                                                  ushort* __restrict__ hr) {
    __shared__ char As[64 * 512];
    __shared__ char Bs[64 * 512];
    int m0 = blockIdx.x * 64;
    int tid = threadIdx.x;
    // stage B chunk 0 + x-part early (coalesced; overlap gather latency)
    for (int j = tid; j < 2048; j += 256)
        *(uint4*)(Bs + swz((j >> 5) * 512 + (j & 31) * 16)) = *(const uint4*)&Wcat[j * 8];
    for (int c = tid; c < 1024; c += 256) {
        int m = c >> 4, kc = c & 15;
        int mm = min(m0 + m, NN - 1);
        *(uint4*)(As + swz(m * 512 + 256 + kc * 16)) =
            *(const uint4*)&xbf[(size_t)mm * 128 + kc * 8];
    }
    gather_into_As(xbf, rowstart, sortedSrc, As, m0, tid);
    __syncthreads();

    int lane = tid & 63, wave = tid >> 6;
    int col = lane & 15, kg = lane >> 4;
    int mym = wave * 16 + col;
    short8 a[8];
#pragma unroll
    for (int ks = 0; ks < 8; ++ks)
        a[ks] = *(const short8*)(As + swz(mym * 512 + (ks * 32 + kg * 8) * 2));
    f32x4 acc[16];
#pragma unroll
    for (int nt = 0; nt < 4; ++nt) {
        f32x4 c = {0.f, 0.f, 0.f, 0.f};
#pragma unroll
        for (int ks = 0; ks < 8; ++ks)
            c = __builtin_amdgcn_mfma_f32_16x16x32_bf16(
                a[ks], *(const short8*)(Bs + swz((nt * 16 + col) * 512 + (ks * 32 + kg * 8) * 2)), c, 0, 0, 0);
        acc[nt] = c;
    }
    for (int ch = 1; ch < 4; ++ch) {
        __syncthreads();
        for (int j = tid; j < 2048; j += 256)
            *(uint4*)(Bs + swz((j >> 5) * 512 + (j & 31) * 16)) =
                *(const uint4*)&Wcat[ch * 16384 + j * 8];
        __syncthreads();
#pragma unroll
        for (int nt = 0; nt < 4; ++nt) {
            f32x4 c = {0.f, 0.f, 0.f, 0.f};
#pragma unroll
            for (int ks = 0; ks < 8; ++ks)
                c = __builtin_amdgcn_mfma_f32_16x16x32_bf16(
                    a[ks], *(const short8*)(Bs + swz((nt * 16 + col) * 512 + (ks * 32 + kg * 8) * 2)), c, 0, 0, 0);
            acc[ch * 4 + nt] = c;
        }
    }
    // bias + l2norm
    float ssq[4] = {0.f, 0.f, 0.f, 0.f};
#pragma unroll
    for (int nt = 0; nt < 16; ++nt) {
        float b = bias1[nt * 16 + col];
#pragma unroll
        for (int r = 0; r < 4; ++r) {
            acc[nt][r] += b;
            ssq[r] += acc[nt][r] * acc[nt][r];
        }
    }
#pragma unroll
    for (int off = 1; off < 16; off <<= 1)
#pragma unroll
        for (int r = 0; r < 4; ++r) ssq[r] += __shfl_xor(ssq[r], off);
    float rn[4];
#pragma unroll
    for (int r = 0; r < 4; ++r) rn[r] = 1.0f / fmaxf(sqrtf(ssq[r]), 1e-12f);
    // write h (bf16) into As (own rows; a[] already in regs)
#pragma unroll
    for (int r = 0; r < 4; ++r) {
        int rl = wave * 16 + kg * 4 + r;
#pragma unroll
        for (int nt = 0; nt < 16; ++nt)
            *(ushort*)(As + swz(rl * 512 + (nt * 16 + col) * 2)) = f2bf(acc[nt][r] * rn[r]);
    }
    __syncthreads();
    // second GEMM: hr = relu(h @ Wlin^T + blin)
    short8 a2[8];
#pragma unroll
    for (int ks = 0; ks < 8; ++ks)
        a2[ks] = *(const short8*)(As + swz(mym * 512 + (ks * 32 + kg * 8) * 2));
    for (int j = tid; j < 2048; j += 256)
        *(uint4*)(Bs + swz((j >> 5) * 512 + (j & 31) * 16)) = *(const uint4*)&Wlin[j * 8];
    __syncthreads();
    f32x4 acc2[8];
#pragma unroll
    for (int nt = 0; nt < 4; ++nt) {
        f32x4 c = {0.f, 0.f, 0.f, 0.f};
#pragma unroll
        for (int ks = 0; ks < 8; ++ks)
            c = __builtin_amdgcn_mfma_f32_16x16x32_bf16(
                a2[ks], *(const short8*)(Bs + swz((nt * 16 + col) * 512 + (ks * 32 + kg * 8) * 2)), c, 0, 0, 0);
        acc2[nt] = c;
    }
    __syncthreads();
    for (int j = tid; j < 2048; j += 256)
        *(uint4*)(Bs + swz((j >> 5) * 512 + (j & 31) * 16)) = *(const uint4*)&Wlin[16384 + j * 8];
    __syncthreads();
#pragma unroll
    for (int nt = 0; nt < 4; ++nt) {
        f32x4 c = {0.f, 0.f, 0.f, 0.f};
#pragma unroll
        for (int ks = 0; ks < 8; ++ks)
            c = __builtin_amdgcn_mfma_f32_16x16x32_bf16(
                a2[ks], *(const short8*)(Bs + swz((nt * 16 + col) * 512 + (ks * 32 + kg * 8) * 2)), c, 0, 0, 0);
        acc2[4 + nt] = c;
    }
#pragma unroll
    for (int r = 0; r < 4; ++r) {
        int node = m0 + wave * 16 + kg * 4 + r;
        if (node < NN) {
#pragma unroll
            for (int nt = 0; nt < 8; ++nt) {
                float vv = acc2[nt][r] + blin[nt * 16 + col];
                hr[(size_t)node * 128 + nt * 16 + col] = f2bf(fmaxf(vv, 0.f));
            }
        }
    }
}

// --- conv2 + linear2 + softmax fused, with in-kernel gather ---
__global__ __launch_bounds__(256) void conv2_g(const ushort* __restrict__ hr,
                                               const int* __restrict__ rowstart,
                                               const int* __restrict__ sortedSrc,
                                               const ushort* __restrict__ Wcat,
                                               const float* __restrict__ bias,
                                               const float* __restrict__ Wlin2,
                                               const float* __restrict__ blin2,
                                               float* __restrict__ probs,
                                               float* __restrict__ yout) {
    __shared__ char As[64 * 512];
    __shared__ char Bs[64 * 512];
    int m0 = blockIdx.x * 64;
    int tid = threadIdx.x;
    for (int j = tid; j < 2048; j += 256)
        *(uint4*)(Bs + swz((j >> 5) * 512 + (j & 31) * 16)) = *(const uint4*)&Wcat[j * 8];
    for (int c = tid; c < 1024; c += 256) {
        int m = c >> 4, kc = c & 15;
        int mm = min(m0 + m, NN - 1);
        *(uint4*)(As + swz(m * 512 + 256 + kc * 16)) =
            *(const uint4*)&hr[(size_t)mm * 128 + kc * 8];
    }
    gather_into_As(hr, rowstart, sortedSrc, As, m0, tid);
    __syncthreads();

    int lane = tid & 63, wave = tid >> 6;
    int col = lane & 15, kg = lane >> 4;
    int mym = wave * 16 + col;
    short8 a[8];
#pragma unroll
    for (int ks = 0; ks < 8; ++ks)
        a[ks] = *(const short8*)(As + swz(mym * 512 + (ks * 32 + kg * 8) * 2));
    f32x4 acc[8];
#pragma unroll
    for (int nt = 0; nt < 4; ++nt) {
        f32x4 c = {0.f, 0.f, 0.f, 0.f};
#pragma unroll
        for (int ks = 0; ks < 8; ++ks)
            c = __builtin_amdgcn_mfma_f32_16x16x32_bf16(
                a[ks], *(const short8*)(Bs + swz((nt * 16 + col) * 512 + (ks * 32 + kg * 8) * 2)), c, 0, 0, 0);
        acc[nt] = c;
    }
    __syncthreads();
    for (int j = tid; j < 2048; j += 256)
        *(uint4*)(Bs + swz((j >> 5) * 512 + (j & 31) * 16)) = *(const uint4*)&Wcat[16384 + j * 8];
    __syncthreads();
#pragma unroll
    for (int nt = 0; nt < 4; ++nt) {
        f32x4 c = {0.f, 0.f, 0.f, 0.f};
#pragma unroll
        for (int ks = 0; ks < 8; ++ks)
            c = __builtin_amdgcn_mfma_f32_16x16x32_bf16(
                a[ks], *(const short8*)(Bs + swz((nt * 16 + col) * 512 + (ks * 32 + kg * 8) * 2)), c, 0, 0, 0);
        acc[4 + nt] = c;
    }
    float ssq[4] = {0.f, 0.f, 0.f, 0.f};
#pragma unroll
    for (int nt = 0; nt < 8; ++nt) {
        float b = bias[nt * 16 + col];
#pragma unroll
        for (int r = 0; r < 4; ++r) {
            acc[nt][r] += b;
            ssq[r] += acc[nt][r] * acc[nt][r];
        }
    }
#pragma unroll
    for (int off = 1; off < 16; off <<= 1)
#pragma unroll
        for (int r = 0; r < 4; ++r) ssq[r] += __shfl_xor(ssq[r], off);
    float rn[4], p0[4] = {0.f,0.f,0.f,0.f}, p1[4] = {0.f,0.f,0.f,0.f};
#pragma unroll
    for (int r = 0; r < 4; ++r) rn[r] = 1.0f / fmaxf(sqrtf(ssq[r]), 1e-12f);
#pragma unroll
    for (int nt = 0; nt < 8; ++nt) {
        float w0 = Wlin2[nt * 16 + col], w1 = Wlin2[128 + nt * 16 + col];
#pragma unroll
        for (int r = 0; r < 4; ++r) {
            float yv = acc[nt][r] * rn[r];
            acc[nt][r] = yv;
            p0[r] += yv * w0;
            p1[r] += yv * w1;
        }
    }
#pragma unroll
    for (int off = 1; off < 16; off <<= 1)
#pragma unroll
        for (int r = 0; r < 4; ++r) { p0[r] += __shfl_xor(p0[r], off); p1[r] += __shfl_xor(p1[r], off); }
#pragma unroll
    for (int r = 0; r < 4; ++r) {
        int node = m0 + wave * 16 + kg * 4 + r;
        if (node < NN) {
#pragma unroll
            for (int nt = 0; nt < 8; ++nt)
                yout[(size_t)node * 128 + nt * 16 + col] = acc[nt][r];
            if (col == 0) {
                float l0 = p0[r] + blin2[0], l1 = p1[r] + blin2[1];
                float mx = fmaxf(l0, l1);
                float e0 = expf(l0 - mx), e1 = expf(l1 - mx);
                float inv = 1.0f / (e0 + e1);
                probs[(size_t)node * 2 + 0] = e0 * inv;
                probs[(size_t)node * 2 + 1] = e1 * inv;
            }
        }
    }
}

extern "C" void kernel_launch(void* const* d_in, const int* in_sizes, int n_in,
                              void* d_out, int out_size, void* d_ws, size_t ws_size,
                              hipStream_t stream) {
    const float* x     = (const float*)d_in[0];
    const int*   ei    = (const int*)d_in[1];
    const int*   src   = ei;
    const int*   tgt   = ei + NE;
    const float* W1l   = (const float*)d_in[2];
    const float* b1l   = (const float*)d_in[3];
    const float* W1r   = (const float*)d_in[4];
    const float* Wlin  = (const float*)d_in[5];
    const float* blin  = (const float*)d_in[6];
    const float* W2l   = (const float*)d_in[7];
    const float* b2l   = (const float*)d_in[8];
    const float* W2r   = (const float*)d_in[9];
    const float* Wlin2 = (const float*)d_in[10];
    const float* blin2 = (const float*)d_in[11];

    float* probs = (float*)d_out;              // [N,2]
    float* y     = (float*)d_out + 2 * NN;     // [N,128]

    // ws layout
    int*    bcnt      = (int*)d_ws;                     // NBK
    int*    bbase     = bcnt + NBK;                     // NBK+1
    int*    bcursor   = bbase + NBK + 1;                // NBK
    int*    rowstart  = bcursor + NBK;                  // NN+1
    uint*   brec      = (uint*)(rowstart + NN + 1);     // NE
    int*    sortedSrc = (int*)(brec + NE);              // NE
    ushort* Wcat1     = (ushort*)(sortedSrc + NE);      // 256*256
    ushort* Wlinb     = Wcat1 + 65536;                  // 128*256
    ushort* Wcat2     = Wlinb + 32768;                  // 128*256
    ushort* xbf       = Wcat2 + 32768;                  // N*128
    ushort* hr        = xbf + (size_t)NN * 128;         // N*128 (separate: xbf gather-read by all blocks)

    const int NEB = (NE + EPB - 1) / EPB;               // 196 edge blocks

    hipMemsetAsync(bcnt, 0, sizeof(int) * NBK, stream);

    prep_w<<<512, 256, 0, stream>>>(W1l, W1r, Wlin, W2l, W2r, Wcat1, Wlinb, Wcat2);
    xcvt<<<NN * 32 / 256, 256, 0, stream>>>(x, xbf);

    bucket_hist<<<NEB, 256, 0, stream>>>(tgt, bcnt);
    bucket_scan<<<1, 256, 0, stream>>>(bcnt, bbase, bcursor, rowstart);
    bucket_scatter<<<NEB, 256, 0, stream>>>(src, tgt, bcursor, brec);
    bucket_to_csr<<<NBK, 256, 0, stream>>>(brec, bbase, rowstart, sortedSrc);

    conv1lin_g<<<(NN + 63) / 64, 256, 0, stream>>>(xbf, rowstart, sortedSrc,
                                                   Wcat1, b1l, Wlinb, blin, hr);
    conv2_g<<<(NN + 63) / 64, 256, 0, stream>>>(hr, rowstart, sortedSrc,
                                                Wcat2, b2l, Wlin2, blin2, probs, y);
}

// Round 9
// 395.494 us; speedup vs baseline: 1.2562x; 1.2562x over previous
//
#include <hip/hip_runtime.h>
#include <hip/hip_bf16.h>
#include <hip/hip_fp8.h>

#define NN   100000
#define NE   1600000
#define NBK  196      // ceil(NN/512) buckets
#define BSH  9        // 512 nodes per bucket
#define EPB  8192     // edges per scatter block
#define CAP  9216     // max edges per bucket

typedef __attribute__((ext_vector_type(8))) short short8;
typedef __attribute__((ext_vector_type(4))) float f32x4;

__device__ __forceinline__ ushort f2bf(float f) {
    union { float f; uint u; } v; v.f = f;
    uint u = v.u;
    return (ushort)((u + 0x7FFFu + ((u >> 16) & 1u)) >> 16);
}
__device__ __forceinline__ float bf2f(uint b) {
    union { uint u; float f; } v; v.u = b << 16;
    return v.f;
}
__device__ __forceinline__ float fp8f(uint byte) {
    __hip_fp8_e4m3 t; t.__x = (__hip_fp8_storage_t)(byte & 0xffu);
    return (float)t;
}
__device__ __forceinline__ uint f2fp8(float f) {
    __hip_fp8_e4m3 t(f);
    return (uint)t.__x;
}
// XOR-swizzle for 512B-stride LDS rows (guide G4)
__device__ __forceinline__ int swz(int off) { return off ^ (((off >> 9) & 7) << 4); }

// ---------------- bucket histogram ----------------
__global__ __launch_bounds__(256) void bucket_hist(const int* __restrict__ tgt,
                                                   int* __restrict__ bcnt) {
    __shared__ int lh[NBK];
    int tid = threadIdx.x;
    for (int i = tid; i < NBK; i += 256) lh[i] = 0;
    __syncthreads();
    int base4 = blockIdx.x * (EPB / 4);
#pragma unroll
    for (int k = 0; k < 8; ++k) {
        int i4 = base4 + k * 256 + tid;
        if (i4 < NE / 4) {
            int4 t = ((const int4*)tgt)[i4];
            atomicAdd(&lh[t.x >> BSH], 1);
            atomicAdd(&lh[t.y >> BSH], 1);
            atomicAdd(&lh[t.z >> BSH], 1);
            atomicAdd(&lh[t.w >> BSH], 1);
        }
    }
    __syncthreads();
    for (int i = tid; i < NBK; i += 256)
        if (lh[i]) atomicAdd(&bcnt[i], lh[i]);
}

// ---------------- bucket scan ----------------
__global__ __launch_bounds__(256) void bucket_scan(const int* __restrict__ bcnt,
                                                   int* __restrict__ bbase,
                                                   int* __restrict__ bcursor,
                                                   int* __restrict__ rowstart) {
    int t = threadIdx.x;
    int v = (t < NBK) ? bcnt[t] : 0;
    int lane = t & 63, wid = t >> 6;
    int inc = v;
#pragma unroll
    for (int off = 1; off < 64; off <<= 1) {
        int u = __shfl_up(inc, off);
        if (lane >= off) inc += u;
    }
    __shared__ int ws[4];
    if (lane == 63) ws[wid] = inc;
    __syncthreads();
    int woff = 0;
    for (int w = 0; w < wid; ++w) woff += ws[w];
    int ex = woff + inc - v;
    if (t < NBK) { bbase[t] = ex; bcursor[t] = ex; }
    if (t == NBK) bbase[NBK] = ex;
    if (t == 255) rowstart[NN] = NE;
}

// ------- bucket scatter -------
__global__ __launch_bounds__(256) void bucket_scatter(const int* __restrict__ src,
                                                      const int* __restrict__ tgt,
                                                      int* __restrict__ bcursor,
                                                      uint* __restrict__ brec) {
    __shared__ int lh[NBK + 1];
    __shared__ int lcur[NBK];
    __shared__ int lbase[NBK];
    __shared__ uint lrec[EPB];
    __shared__ int ws[4];
    int tid = threadIdx.x;
    for (int i = tid; i < NBK; i += 256) lh[i] = 0;
    __syncthreads();
    int base4 = blockIdx.x * (EPB / 4);
#pragma unroll
    for (int k = 0; k < 8; ++k) {
        int i4 = base4 + k * 256 + tid;
        if (i4 < NE / 4) {
            int4 t = ((const int4*)tgt)[i4];
            atomicAdd(&lh[t.x >> BSH], 1);
            atomicAdd(&lh[t.y >> BSH], 1);
            atomicAdd(&lh[t.z >> BSH], 1);
            atomicAdd(&lh[t.w >> BSH], 1);
        }
    }
    __syncthreads();
    int v = (tid < NBK) ? lh[tid] : 0;
    int lane = tid & 63, wid = tid >> 6;
    int inc = v;
#pragma unroll
    for (int off = 1; off < 64; off <<= 1) {
        int u = __shfl_up(inc, off);
        if (lane >= off) inc += u;
    }
    if (lane == 63) ws[wid] = inc;
    __syncthreads();
    int woff = 0;
    for (int w = 0; w < wid; ++w) woff += ws[w];
    int ex = woff + inc - v;
    int nval = min(EPB, NE - blockIdx.x * EPB);
    if (tid < NBK) {
        lh[tid] = ex;
        lcur[tid] = ex;
        lbase[tid] = v ? atomicAdd(&bcursor[tid], v) : 0;
    }
    if (tid == 0) lh[NBK] = nval;
    __syncthreads();
#pragma unroll
    for (int k = 0; k < 8; ++k) {
        int i4 = base4 + k * 256 + tid;
        if (i4 < NE / 4) {
            int4 t = ((const int4*)tgt)[i4];
            int4 s = ((const int4*)src)[i4];
            int p;
            p = atomicAdd(&lcur[t.x >> BSH], 1); lrec[p] = ((uint)s.x << BSH) | (uint)(t.x & 511);
            p = atomicAdd(&lcur[t.y >> BSH], 1); lrec[p] = ((uint)s.y << BSH) | (uint)(t.y & 511);
            p = atomicAdd(&lcur[t.z >> BSH], 1); lrec[p] = ((uint)s.z << BSH) | (uint)(t.z & 511);
            p = atomicAdd(&lcur[t.w >> BSH], 1); lrec[p] = ((uint)s.w << BSH) | (uint)(t.w & 511);
        }
    }
    __syncthreads();
    for (int i = tid; i < nval; i += 256) {
        int lo = 0, hi = NBK;
        while (hi - lo > 1) { int mid = (lo + hi) >> 1; if (lh[mid] <= i) lo = mid; else hi = mid; }
        brec[lbase[lo] + (i - lh[lo])] = lrec[i];
    }
}

// ------- bucket -> CSR (+ per-node src-sort for gather L2 locality) -------
__global__ __launch_bounds__(256) void bucket_to_csr(const uint* __restrict__ brec,
                                                     const int* __restrict__ bbase,
                                                     int* __restrict__ rowstart,
                                                     int* __restrict__ sortedSrc) {
    __shared__ int cnt[512];
    __shared__ int cur[512];
    __shared__ int srt[CAP];
    __shared__ int ws[4];
    int b = blockIdx.x;
    int beg = bbase[b], end = bbase[b + 1];
    int len = end - beg;
    int n0 = b << BSH;
    int ncnt = min(512, NN - n0);
    int tid = threadIdx.x;
    cnt[tid] = 0; cnt[tid + 256] = 0;
    __syncthreads();
    for (int i = beg + tid; i < end; i += 256)
        atomicAdd(&cnt[brec[i] & 511u], 1);
    __syncthreads();
    int c0 = cnt[2 * tid], c1 = cnt[2 * tid + 1];
    int s = c0 + c1;
    int lane = tid & 63, wid = tid >> 6;
    int inc = s;
#pragma unroll
    for (int off = 1; off < 64; off <<= 1) {
        int u = __shfl_up(inc, off);
        if (lane >= off) inc += u;
    }
    if (lane == 63) ws[wid] = inc;
    __syncthreads();
    int woff = 0;
    for (int w = 0; w < wid; ++w) woff += ws[w];
    int ex = woff + inc - s;
    cur[2 * tid] = ex; cur[2 * tid + 1] = ex + c0;
    if (2 * tid < ncnt)     rowstart[n0 + 2 * tid]     = beg + ex;
    if (2 * tid + 1 < ncnt) rowstart[n0 + 2 * tid + 1] = beg + ex + c0;
    __syncthreads();
    if (len <= CAP) {
        for (int i = beg + tid; i < end; i += 256) {
            uint r = brec[i];
            int p = atomicAdd(&cur[r & 511u], 1);
            srt[p] = (int)(r >> BSH);
        }
        __syncthreads();
        // per-node insertion sort by src (ascending) -> order-statistic
        // lockstep across waves improves per-XCD L2 reuse in the gather
        for (int j = tid; j < 512; j += 256) {
            int e = cur[j], s2 = e - cnt[j];
            for (int a2 = s2 + 1; a2 < e; ++a2) {
                int key = srt[a2];
                int bb = a2 - 1;
                while (bb >= s2 && srt[bb] > key) { srt[bb + 1] = srt[bb]; --bb; }
                srt[bb + 1] = key;
            }
        }
        __syncthreads();
        for (int i = tid; i < len; i += 256)
            sortedSrc[beg + i] = srt[i];
    } else {  // statistically unreachable fallback (unsorted)
        for (int i = beg + tid; i < end; i += 256) {
            uint r = brec[i];
            int p = atomicAdd(&cur[r & 511u], 1);
            sortedSrc[beg + p] = (int)(r >> BSH);
        }
    }
}

// --- gather mean (fp8 table): wave/node, half-wave/edge, 4B/lane, unroll-2 ---
__global__ __launch_bounds__(256) void gather_mean8(const uchar* __restrict__ t8,
                                                    const int* __restrict__ rowstart,
                                                    const int* __restrict__ sortedSrc,
                                                    ushort* __restrict__ mean) {
    int node = blockIdx.x * 4 + (threadIdx.x >> 6);
    if (node >= NN) return;
    int lane = threadIdx.x & 63;
    int half = lane >> 5, l = lane & 31;
    int beg = rowstart[node], end = rowstart[node + 1];
    float a0 = 0.f, a1 = 0.f, a2 = 0.f, a3 = 0.f;
    float b0 = 0.f, b1 = 0.f, b2 = 0.f, b3 = 0.f;
    int i = beg + half;
    for (; i + 2 < end; i += 4) {
        int s0 = sortedSrc[i], s1 = sortedSrc[i + 2];
        uint v0 = *(const uint*)&t8[(size_t)s0 * 128 + l * 4];
        uint v1 = *(const uint*)&t8[(size_t)s1 * 128 + l * 4];
        a0 += fp8f(v0);       a1 += fp8f(v0 >> 8);
        a2 += fp8f(v0 >> 16); a3 += fp8f(v0 >> 24);
        b0 += fp8f(v1);       b1 += fp8f(v1 >> 8);
        b2 += fp8f(v1 >> 16); b3 += fp8f(v1 >> 24);
    }
    if (i < end) {
        int s0 = sortedSrc[i];
        uint v0 = *(const uint*)&t8[(size_t)s0 * 128 + l * 4];
        a0 += fp8f(v0);       a1 += fp8f(v0 >> 8);
        a2 += fp8f(v0 >> 16); a3 += fp8f(v0 >> 24);
    }
    a0 += b0; a1 += b1; a2 += b2; a3 += b3;
    a0 += __shfl_xor(a0, 32); a1 += __shfl_xor(a1, 32);
    a2 += __shfl_xor(a2, 32); a3 += __shfl_xor(a3, 32);
    if (half == 0) {
        float id = 1.0f / fmaxf((float)(end - beg), 1.0f);
        ushort4 p;
        p.x = f2bf(a0 * id); p.y = f2bf(a1 * id);
        p.z = f2bf(a2 * id); p.w = f2bf(a3 * id);
        *(ushort4*)&mean[(size_t)node * 128 + l * 4] = p;
    }
}

// ---------------- weight prep ----------------
__global__ __launch_bounds__(256) void prep_w(const float* __restrict__ W1l,
                                              const float* __restrict__ W1r,
                                              const float* __restrict__ Wlin,
                                              const float* __restrict__ W2l,
                                              const float* __restrict__ W2r,
                                              ushort* __restrict__ Wcat1,
                                              ushort* __restrict__ Wlinb,
                                              ushort* __restrict__ Wcat2) {
    int i = blockIdx.x * 256 + threadIdx.x;
    if (i < 65536) {
        int o = i >> 8, k = i & 255;
        float v = (k < 128) ? W1l[o * 128 + k] : W1r[o * 128 + k - 128];
        Wcat1[i] = f2bf(v);
    } else if (i < 98304) {
        int j = i - 65536;
        Wlinb[j] = f2bf(Wlin[j]);
    } else {
        int j = i - 98304;
        int o = j >> 8, k = j & 255;
        float v = (k < 128) ? W2l[o * 128 + k] : W2r[o * 128 + k - 128];
        Wcat2[j] = f2bf(v);
    }
}

// ---------------- x fp32 -> bf16 + fp8 ----------------
__global__ __launch_bounds__(256) void xcvt(const float* __restrict__ x,
                                            ushort* __restrict__ xbf,
                                            uchar* __restrict__ x8) {
    int i = blockIdx.x * 256 + threadIdx.x;   // over NN*128/4
    float4 v = ((const float4*)x)[i];
    ushort4 p;
    p.x = f2bf(v.x); p.y = f2bf(v.y); p.z = f2bf(v.z); p.w = f2bf(v.w);
    ((ushort4*)xbf)[i] = p;
    uint q = f2fp8(v.x) | (f2fp8(v.y) << 8) | (f2fp8(v.z) << 16) | (f2fp8(v.w) << 24);
    ((uint*)x8)[i] = q;
}

// ---------------- hr bf16 -> fp8 ----------------
__global__ __launch_bounds__(256) void cvt8(const ushort* __restrict__ hr,
                                            uchar* __restrict__ hr8) {
    int i = blockIdx.x * 256 + threadIdx.x;   // over NN*128/8
    uint4 v = ((const uint4*)hr)[i];
    uint lo = f2fp8(bf2f(v.x & 0xffffu)) | (f2fp8(bf2f(v.x >> 16)) << 8) |
              (f2fp8(bf2f(v.y & 0xffffu)) << 16) | (f2fp8(bf2f(v.y >> 16)) << 24);
    uint hi = f2fp8(bf2f(v.z & 0xffffu)) | (f2fp8(bf2f(v.z >> 16)) << 8) |
              (f2fp8(bf2f(v.w & 0xffffu)) << 16) | (f2fp8(bf2f(v.w >> 16)) << 24);
    uint2 o; o.x = lo; o.y = hi;
    ((uint2*)hr8)[i] = o;
}

// --- conv1+linear fused: h = l2norm([mean|x]@Wcat1^T + b1), hr = relu(h@Wlin^T + blin)
__global__ __launch_bounds__(256) void conv1lin_mfma(const ushort* __restrict__ mean,
                                                     const ushort* __restrict__ xbf,
                                                     const ushort* __restrict__ Wcat,
                                                     const float* __restrict__ bias1,
                                                     const ushort* __restrict__ Wlin,
                                                     const float* __restrict__ blin,
                                                     ushort* __restrict__ hr) {
    __shared__ char As[64 * 512];
    __shared__ char Bs[64 * 512];
    int m0 = blockIdx.x * 64;
    int tid = threadIdx.x;
    for (int c = tid; c < 2048; c += 256) {
        int m = c >> 5, kc = c & 31;
        int mm = min(m0 + m, NN - 1);
        uint4 v = (kc < 16) ? *(const uint4*)&mean[(size_t)mm * 128 + kc * 8]
                            : *(const uint4*)&xbf[(size_t)mm * 128 + (kc - 16) * 8];
        *(uint4*)(As + swz(m * 512 + kc * 16)) = v;
    }
    for (int j = tid; j < 2048; j += 256)
        *(uint4*)(Bs + swz((j >> 5) * 512 + (j & 31) * 16)) = *(const uint4*)&Wcat[j * 8];
    __syncthreads();

    int lane = tid & 63, wave = tid >> 6;
    int col = lane & 15, kg = lane >> 4;
    int mym = wave * 16 + col;
    short8 a[8];
#pragma unroll
    for (int ks = 0; ks < 8; ++ks)
        a[ks] = *(const short8*)(As + swz(mym * 512 + (ks * 32 + kg * 8) * 2));
    f32x4 acc[16];
#pragma unroll
    for (int nt = 0; nt < 4; ++nt) {
        f32x4 c = {0.f, 0.f, 0.f, 0.f};
#pragma unroll
        for (int ks = 0; ks < 8; ++ks)
            c = __builtin_amdgcn_mfma_f32_16x16x32_bf16(
                a[ks], *(const short8*)(Bs + swz((nt * 16 + col) * 512 + (ks * 32 + kg * 8) * 2)), c, 0, 0, 0);
        acc[nt] = c;
    }
    for (int ch = 1; ch < 4; ++ch) {
        __syncthreads();
        for (int j = tid; j < 2048; j += 256)
            *(uint4*)(Bs + swz((j >> 5) * 512 + (j & 31) * 16)) =
                *(const uint4*)&Wcat[ch * 16384 + j * 8];
        __syncthreads();
#pragma unroll
        for (int nt = 0; nt < 4; ++nt) {
            f32x4 c = {0.f, 0.f, 0.f, 0.f};
#pragma unroll
            for (int ks = 0; ks < 8; ++ks)
                c = __builtin_amdgcn_mfma_f32_16x16x32_bf16(
                    a[ks], *(const short8*)(Bs + swz((nt * 16 + col) * 512 + (ks * 32 + kg * 8) * 2)), c, 0, 0, 0);
            acc[ch * 4 + nt] = c;
        }
    }
    // bias + l2norm
    float ssq[4] = {0.f, 0.f, 0.f, 0.f};
#pragma unroll
    for (int nt = 0; nt < 16; ++nt) {
        float b = bias1[nt * 16 + col];
#pragma unroll
        for (int r = 0; r < 4; ++r) {
            acc[nt][r] += b;
            ssq[r] += acc[nt][r] * acc[nt][r];
        }
    }
#pragma unroll
    for (int off = 1; off < 16; off <<= 1)
#pragma unroll
        for (int r = 0; r < 4; ++r) ssq[r] += __shfl_xor(ssq[r], off);
    float rn[4];
#pragma unroll
    for (int r = 0; r < 4; ++r) rn[r] = 1.0f / fmaxf(sqrtf(ssq[r]), 1e-12f);
    // write h (bf16) into As
#pragma unroll
    for (int r = 0; r < 4; ++r) {
        int rl = wave * 16 + kg * 4 + r;
#pragma unroll
        for (int nt = 0; nt < 16; ++nt)
            *(ushort*)(As + swz(rl * 512 + (nt * 16 + col) * 2)) = f2bf(acc[nt][r] * rn[r]);
    }
    __syncthreads();
    // second GEMM: hr = relu(h @ Wlin^T + blin)
    short8 a2[8];
#pragma unroll
    for (int ks = 0; ks < 8; ++ks)
        a2[ks] = *(const short8*)(As + swz(mym * 512 + (ks * 32 + kg * 8) * 2));
    for (int j = tid; j < 2048; j += 256)
        *(uint4*)(Bs + swz((j >> 5) * 512 + (j & 31) * 16)) = *(const uint4*)&Wlin[j * 8];
    __syncthreads();
    f32x4 acc2[8];
#pragma unroll
    for (int nt = 0; nt < 4; ++nt) {
        f32x4 c = {0.f, 0.f, 0.f, 0.f};
#pragma unroll
        for (int ks = 0; ks < 8; ++ks)
            c = __builtin_amdgcn_mfma_f32_16x16x32_bf16(
                a2[ks], *(const short8*)(Bs + swz((nt * 16 + col) * 512 + (ks * 32 + kg * 8) * 2)), c, 0, 0, 0);
        acc2[nt] = c;
    }
    __syncthreads();
    for (int j = tid; j < 2048; j += 256)
        *(uint4*)(Bs + swz((j >> 5) * 512 + (j & 31) * 16)) = *(const uint4*)&Wlin[16384 + j * 8];
    __syncthreads();
#pragma unroll
    for (int nt = 0; nt < 4; ++nt) {
        f32x4 c = {0.f, 0.f, 0.f, 0.f};
#pragma unroll
        for (int ks = 0; ks < 8; ++ks)
            c = __builtin_amdgcn_mfma_f32_16x16x32_bf16(
                a2[ks], *(const short8*)(Bs + swz((nt * 16 + col) * 512 + (ks * 32 + kg * 8) * 2)), c, 0, 0, 0);
        acc2[4 + nt] = c;
    }
#pragma unroll
    for (int r = 0; r < 4; ++r) {
        int node = m0 + wave * 16 + kg * 4 + r;
        if (node < NN) {
#pragma unroll
            for (int nt = 0; nt < 8; ++nt) {
                float vv = acc2[nt][r] + blin[nt * 16 + col];
                hr[(size_t)node * 128 + nt * 16 + col] = f2bf(fmaxf(vv, 0.f));
            }
        }
    }
}

// ------- conv2 + linear2 + softmax -------
__global__ __launch_bounds__(256) void conv2_mfma(const ushort* __restrict__ mean,
                                                  const ushort* __restrict__ hr,
                                                  const ushort* __restrict__ Wcat,
                                                  const float* __restrict__ bias,
                                                  const float* __restrict__ Wlin2,
                                                  const float* __restrict__ blin2,
                                                  float* __restrict__ probs,
                                                  float* __restrict__ yout) {
    __shared__ char As[64 * 512];
    __shared__ char Bs[64 * 512];
    int m0 = blockIdx.x * 64;
    int tid = threadIdx.x;
    for (int c = tid; c < 2048; c += 256) {
        int m = c >> 5, kc = c & 31;
        int mm = min(m0 + m, NN - 1);
        uint4 v = (kc < 16) ? *(const uint4*)&mean[(size_t)mm * 128 + kc * 8]
                            : *(const uint4*)&hr[(size_t)mm * 128 + (kc - 16) * 8];
        *(uint4*)(As + swz(m * 512 + kc * 16)) = v;
    }
    for (int j = tid; j < 2048; j += 256)
        *(uint4*)(Bs + swz((j >> 5) * 512 + (j & 31) * 16)) = *(const uint4*)&Wcat[j * 8];
    __syncthreads();

    int lane = tid & 63, wave = tid >> 6;
    int col = lane & 15, kg = lane >> 4;
    int mym = wave * 16 + col;
    short8 a[8];
#pragma unroll
    for (int ks = 0; ks < 8; ++ks)
        a[ks] = *(const short8*)(As + swz(mym * 512 + (ks * 32 + kg * 8) * 2));
    f32x4 acc[8];
#pragma unroll
    for (int nt = 0; nt < 4; ++nt) {
        f32x4 c = {0.f, 0.f, 0.f, 0.f};
#pragma unroll
        for (int ks = 0; ks < 8; ++ks)
            c = __builtin_amdgcn_mfma_f32_16x16x32_bf16(
                a[ks], *(const short8*)(Bs + swz((nt * 16 + col) * 512 + (ks * 32 + kg * 8) * 2)), c, 0, 0, 0);
        acc[nt] = c;
    }
    __syncthreads();
    for (int j = tid; j < 2048; j += 256)
        *(uint4*)(Bs + swz((j >> 5) * 512 + (j & 31) * 16)) = *(const uint4*)&Wcat[16384 + j * 8];
    __syncthreads();
#pragma unroll
    for (int nt = 0; nt < 4; ++nt) {
        f32x4 c = {0.f, 0.f, 0.f, 0.f};
#pragma unroll
        for (int ks = 0; ks < 8; ++ks)
            c = __builtin_amdgcn_mfma_f32_16x16x32_bf16(
                a[ks], *(const short8*)(Bs + swz((nt * 16 + col) * 512 + (ks * 32 + kg * 8) * 2)), c, 0, 0, 0);
        acc[4 + nt] = c;
    }
    float ssq[4] = {0.f, 0.f, 0.f, 0.f};
#pragma unroll
    for (int nt = 0; nt < 8; ++nt) {
        float b = bias[nt * 16 + col];
#pragma unroll
        for (int r = 0; r < 4; ++r) {
            acc[nt][r] += b;
            ssq[r] += acc[nt][r] * acc[nt][r];
        }
    }
#pragma unroll
    for (int off = 1; off < 16; off <<= 1)
#pragma unroll
        for (int r = 0; r < 4; ++r) ssq[r] += __shfl_xor(ssq[r], off);
    float rn[4], p0[4] = {0.f,0.f,0.f,0.f}, p1[4] = {0.f,0.f,0.f,0.f};
#pragma unroll
    for (int r = 0; r < 4; ++r) rn[r] = 1.0f / fmaxf(sqrtf(ssq[r]), 1e-12f);
#pragma unroll
    for (int nt = 0; nt < 8; ++nt) {
        float w0 = Wlin2[nt * 16 + col], w1 = Wlin2[128 + nt * 16 + col];
#pragma unroll
        for (int r = 0; r < 4; ++r) {
            float yv = acc[nt][r] * rn[r];
            acc[nt][r] = yv;
            p0[r] += yv * w0;
            p1[r] += yv * w1;
        }
    }
#pragma unroll
    for (int off = 1; off < 16; off <<= 1)
#pragma unroll
        for (int r = 0; r < 4; ++r) { p0[r] += __shfl_xor(p0[r], off); p1[r] += __shfl_xor(p1[r], off); }
#pragma unroll
    for (int r = 0; r < 4; ++r) {
        int node = m0 + wave * 16 + kg * 4 + r;
        if (node < NN) {
#pragma unroll
            for (int nt = 0; nt < 8; ++nt)
                yout[(size_t)node * 128 + nt * 16 + col] = acc[nt][r];
            if (col == 0) {
                float l0 = p0[r] + blin2[0], l1 = p1[r] + blin2[1];
                float mx = fmaxf(l0, l1);
                float e0 = expf(l0 - mx), e1 = expf(l1 - mx);
                float inv = 1.0f / (e0 + e1);
                probs[(size_t)node * 2 + 0] = e0 * inv;
                probs[(size_t)node * 2 + 1] = e1 * inv;
            }
        }
    }
}

extern "C" void kernel_launch(void* const* d_in, const int* in_sizes, int n_in,
                              void* d_out, int out_size, void* d_ws, size_t ws_size,
                              hipStream_t stream) {
    const float* x     = (const float*)d_in[0];
    const int*   ei    = (const int*)d_in[1];
    const int*   src   = ei;
    const int*   tgt   = ei + NE;
    const float* W1l   = (const float*)d_in[2];
    const float* b1l   = (const float*)d_in[3];
    const float* W1r   = (const float*)d_in[4];
    const float* Wlin  = (const float*)d_in[5];
    const float* blin  = (const float*)d_in[6];
    const float* W2l   = (const float*)d_in[7];
    const float* b2l   = (const float*)d_in[8];
    const float* W2r   = (const float*)d_in[9];
    const float* Wlin2 = (const float*)d_in[10];
    const float* blin2 = (const float*)d_in[11];

    float* probs = (float*)d_out;              // [N,2]
    float* y     = (float*)d_out + 2 * NN;     // [N,128]

    // ws layout
    int*    bcnt      = (int*)d_ws;                     // NBK
    int*    bbase     = bcnt + NBK;                     // NBK+1
    int*    bcursor   = bbase + NBK + 1;                // NBK
    int*    rowstart  = bcursor + NBK;                  // NN+1
    uint*   brec      = (uint*)(rowstart + NN + 1);     // NE
    int*    sortedSrc = (int*)(brec + NE);              // NE
    ushort* Wcat1     = (ushort*)(sortedSrc + NE);      // 256*256
    ushort* Wlinb     = Wcat1 + 65536;                  // 128*256
    ushort* Wcat2     = Wlinb + 32768;                  // 128*256
    ushort* xbf       = Wcat2 + 32768;                  // N*128 bf16
    ushort* hr        = xbf + (size_t)NN * 128;         // N*128 bf16
    ushort* mean      = hr + (size_t)NN * 128;          // N*128 bf16
    uchar*  x8        = (uchar*)(mean + (size_t)NN * 128); // N*128 fp8
    uchar*  hr8       = x8 + (size_t)NN * 128;          // N*128 fp8

    const int NEB = (NE + EPB - 1) / EPB;               // 196 edge blocks

    hipMemsetAsync(bcnt, 0, sizeof(int) * NBK, stream);

    prep_w<<<512, 256, 0, stream>>>(W1l, W1r, Wlin, W2l, W2r, Wcat1, Wlinb, Wcat2);
    xcvt<<<NN * 32 / 256, 256, 0, stream>>>(x, xbf, x8);

    bucket_hist<<<NEB, 256, 0, stream>>>(tgt, bcnt);
    bucket_scan<<<1, 256, 0, stream>>>(bcnt, bbase, bcursor, rowstart);
    bucket_scatter<<<NEB, 256, 0, stream>>>(src, tgt, bcursor, brec);
    bucket_to_csr<<<NBK, 256, 0, stream>>>(brec, bbase, rowstart, sortedSrc);

    gather_mean8<<<(NN + 3) / 4, 256, 0, stream>>>(x8, rowstart, sortedSrc, mean);
    conv1lin_mfma<<<(NN + 63) / 64, 256, 0, stream>>>(mean, xbf, Wcat1, b1l,
                                                      Wlinb, blin, hr);
    cvt8<<<NN * 128 / 8 / 256, 256, 0, stream>>>(hr, hr8);
    gather_mean8<<<(NN + 3) / 4, 256, 0, stream>>>(hr8, rowstart, sortedSrc, mean);
    conv2_mfma<<<(NN + 63) / 64, 256, 0, stream>>>(mean, hr, Wcat2, b2l,
                                                   Wlin2, blin2, probs, y);
}

// Round 10
// 306.473 us; speedup vs baseline: 1.6211x; 1.2905x over previous
//
#include <hip/hip_runtime.h>
#include <hip/hip_bf16.h>
#include <hip/hip_fp8.h>

#define NN   100000
#define NE   1600000
#define NBK  196      // ceil(NN/512) buckets
#define BSH  9        // 512 nodes per bucket
#define EPB  8192     // edges per scatter block
#define CAP  9216     // max edges per bucket

typedef __attribute__((ext_vector_type(8))) short short8;
typedef __attribute__((ext_vector_type(4))) float f32x4;

__device__ __forceinline__ ushort f2bf(float f) {
    union { float f; uint u; } v; v.f = f;
    uint u = v.u;
    return (ushort)((u + 0x7FFFu + ((u >> 16) & 1u)) >> 16);
}
__device__ __forceinline__ float bf2f(uint b) {
    union { uint u; float f; } v; v.u = b << 16;
    return v.f;
}
__device__ __forceinline__ float fp8f(uint byte) {
    __hip_fp8_e4m3 t; t.__x = (__hip_fp8_storage_t)(byte & 0xffu);
    return (float)t;
}
__device__ __forceinline__ uint f2fp8(float f) {
    __hip_fp8_e4m3 t(f);
    return (uint)t.__x;
}
// XOR-swizzle for 512B-stride LDS rows (guide G4)
__device__ __forceinline__ int swz(int off) { return off ^ (((off >> 9) & 7) << 4); }

// ---------------- bucket histogram ----------------
__global__ __launch_bounds__(256) void bucket_hist(const int* __restrict__ tgt,
                                                   int* __restrict__ bcnt) {
    __shared__ int lh[NBK];
    int tid = threadIdx.x;
    for (int i = tid; i < NBK; i += 256) lh[i] = 0;
    __syncthreads();
    int base4 = blockIdx.x * (EPB / 4);
#pragma unroll
    for (int k = 0; k < 8; ++k) {
        int i4 = base4 + k * 256 + tid;
        if (i4 < NE / 4) {
            int4 t = ((const int4*)tgt)[i4];
            atomicAdd(&lh[t.x >> BSH], 1);
            atomicAdd(&lh[t.y >> BSH], 1);
            atomicAdd(&lh[t.z >> BSH], 1);
            atomicAdd(&lh[t.w >> BSH], 1);
        }
    }
    __syncthreads();
    for (int i = tid; i < NBK; i += 256)
        if (lh[i]) atomicAdd(&bcnt[i], lh[i]);
}

// ---------------- bucket scan ----------------
__global__ __launch_bounds__(256) void bucket_scan(const int* __restrict__ bcnt,
                                                   int* __restrict__ bbase,
                                                   int* __restrict__ bcursor,
                                                   int* __restrict__ rowstart) {
    int t = threadIdx.x;
    int v = (t < NBK) ? bcnt[t] : 0;
    int lane = t & 63, wid = t >> 6;
    int inc = v;
#pragma unroll
    for (int off = 1; off < 64; off <<= 1) {
        int u = __shfl_up(inc, off);
        if (lane >= off) inc += u;
    }
    __shared__ int ws[4];
    if (lane == 63) ws[wid] = inc;
    __syncthreads();
    int woff = 0;
    for (int w = 0; w < wid; ++w) woff += ws[w];
    int ex = woff + inc - v;
    if (t < NBK) { bbase[t] = ex; bcursor[t] = ex; }
    if (t == NBK) bbase[NBK] = ex;
    if (t == 255) rowstart[NN] = NE;
}

// ------- bucket scatter -------
__global__ __launch_bounds__(256) void bucket_scatter(const int* __restrict__ src,
                                                      const int* __restrict__ tgt,
                                                      int* __restrict__ bcursor,
                                                      uint* __restrict__ brec) {
    __shared__ int lh[NBK + 1];
    __shared__ int lcur[NBK];
    __shared__ int lbase[NBK];
    __shared__ uint lrec[EPB];
    __shared__ int ws[4];
    int tid = threadIdx.x;
    for (int i = tid; i < NBK; i += 256) lh[i] = 0;
    __syncthreads();
    int base4 = blockIdx.x * (EPB / 4);
#pragma unroll
    for (int k = 0; k < 8; ++k) {
        int i4 = base4 + k * 256 + tid;
        if (i4 < NE / 4) {
            int4 t = ((const int4*)tgt)[i4];
            atomicAdd(&lh[t.x >> BSH], 1);
            atomicAdd(&lh[t.y >> BSH], 1);
            atomicAdd(&lh[t.z >> BSH], 1);
            atomicAdd(&lh[t.w >> BSH], 1);
        }
    }
    __syncthreads();
    int v = (tid < NBK) ? lh[tid] : 0;
    int lane = tid & 63, wid = tid >> 6;
    int inc = v;
#pragma unroll
    for (int off = 1; off < 64; off <<= 1) {
        int u = __shfl_up(inc, off);
        if (lane >= off) inc += u;
    }
    if (lane == 63) ws[wid] = inc;
    __syncthreads();
    int woff = 0;
    for (int w = 0; w < wid; ++w) woff += ws[w];
    int ex = woff + inc - v;
    int nval = min(EPB, NE - blockIdx.x * EPB);
    if (tid < NBK) {
        lh[tid] = ex;
        lcur[tid] = ex;
        lbase[tid] = v ? atomicAdd(&bcursor[tid], v) : 0;
    }
    if (tid == 0) lh[NBK] = nval;
    __syncthreads();
#pragma unroll
    for (int k = 0; k < 8; ++k) {
        int i4 = base4 + k * 256 + tid;
        if (i4 < NE / 4) {
            int4 t = ((const int4*)tgt)[i4];
            int4 s = ((const int4*)src)[i4];
            int p;
            p = atomicAdd(&lcur[t.x >> BSH], 1); lrec[p] = ((uint)s.x << BSH) | (uint)(t.x & 511);
            p = atomicAdd(&lcur[t.y >> BSH], 1); lrec[p] = ((uint)s.y << BSH) | (uint)(t.y & 511);
            p = atomicAdd(&lcur[t.z >> BSH], 1); lrec[p] = ((uint)s.z << BSH) | (uint)(t.z & 511);
            p = atomicAdd(&lcur[t.w >> BSH], 1); lrec[p] = ((uint)s.w << BSH) | (uint)(t.w & 511);
        }
    }
    __syncthreads();
    for (int i = tid; i < nval; i += 256) {
        int lo = 0, hi = NBK;
        while (hi - lo > 1) { int mid = (lo + hi) >> 1; if (lh[mid] <= i) lo = mid; else hi = mid; }
        brec[lbase[lo] + (i - lh[lo])] = lrec[i];
    }
}

// ------- bucket -> CSR (no sort; bucketing already gives locality) -------
__global__ __launch_bounds__(256) void bucket_to_csr(const uint* __restrict__ brec,
                                                     const int* __restrict__ bbase,
                                                     int* __restrict__ rowstart,
                                                     int* __restrict__ sortedSrc) {
    __shared__ int cnt[512];
    __shared__ int cur[512];
    __shared__ int srt[CAP];
    __shared__ int ws[4];
    int b = blockIdx.x;
    int beg = bbase[b], end = bbase[b + 1];
    int len = end - beg;
    int n0 = b << BSH;
    int ncnt = min(512, NN - n0);
    int tid = threadIdx.x;
    cnt[tid] = 0; cnt[tid + 256] = 0;
    __syncthreads();
    for (int i = beg + tid; i < end; i += 256)
        atomicAdd(&cnt[brec[i] & 511u], 1);
    __syncthreads();
    int c0 = cnt[2 * tid], c1 = cnt[2 * tid + 1];
    int s = c0 + c1;
    int lane = tid & 63, wid = tid >> 6;
    int inc = s;
#pragma unroll
    for (int off = 1; off < 64; off <<= 1) {
        int u = __shfl_up(inc, off);
        if (lane >= off) inc += u;
    }
    if (lane == 63) ws[wid] = inc;
    __syncthreads();
    int woff = 0;
    for (int w = 0; w < wid; ++w) woff += ws[w];
    int ex = woff + inc - s;
    cur[2 * tid] = ex; cur[2 * tid + 1] = ex + c0;
    if (2 * tid < ncnt)     rowstart[n0 + 2 * tid]     = beg + ex;
    if (2 * tid + 1 < ncnt) rowstart[n0 + 2 * tid + 1] = beg + ex + c0;
    __syncthreads();
    if (len <= CAP) {
        for (int i = beg + tid; i < end; i += 256) {
            uint r = brec[i];
            int p = atomicAdd(&cur[r & 511u], 1);
            srt[p] = (int)(r >> BSH);
        }
        __syncthreads();
        for (int i = tid; i < len; i += 256)
            sortedSrc[beg + i] = srt[i];
    } else {  // statistically unreachable fallback
        for (int i = beg + tid; i < end; i += 256) {
            uint r = brec[i];
            int p = atomicAdd(&cur[r & 511u], 1);
            sortedSrc[beg + p] = (int)(r >> BSH);
        }
    }
}

// --- gather mean (fp8): wave/node, quarter-wave/edge, 8B/lane, unroll-2 ---
__global__ __launch_bounds__(256) void gather_mean8(const uchar* __restrict__ t8,
                                                    const int* __restrict__ rowstart,
                                                    const int* __restrict__ sortedSrc,
                                                    ushort* __restrict__ mean) {
    int node = blockIdx.x * 4 + (threadIdx.x >> 6);
    if (node >= NN) return;
    int lane = threadIdx.x & 63;
    int q = lane >> 4, l = lane & 15;
    int beg = rowstart[node], end = rowstart[node + 1];
    float a0 = 0.f, a1 = 0.f, a2 = 0.f, a3 = 0.f;
    float a4 = 0.f, a5 = 0.f, a6 = 0.f, a7 = 0.f;
    float b0 = 0.f, b1 = 0.f, b2 = 0.f, b3 = 0.f;
    float b4 = 0.f, b5 = 0.f, b6 = 0.f, b7 = 0.f;
#define ACCA(v) { a0 += fp8f(v.x);       a1 += fp8f(v.x >> 8); \
                  a2 += fp8f(v.x >> 16); a3 += fp8f(v.x >> 24); \
                  a4 += fp8f(v.y);       a5 += fp8f(v.y >> 8); \
                  a6 += fp8f(v.y >> 16); a7 += fp8f(v.y >> 24); }
#define ACCB(v) { b0 += fp8f(v.x);       b1 += fp8f(v.x >> 8); \
                  b2 += fp8f(v.x >> 16); b3 += fp8f(v.x >> 24); \
                  b4 += fp8f(v.y);       b5 += fp8f(v.y >> 8); \
                  b6 += fp8f(v.y >> 16); b7 += fp8f(v.y >> 24); }
    int i = beg + q;
    for (; i + 4 < end; i += 8) {
        int s0 = sortedSrc[i];
        int s1 = sortedSrc[i + 4];
        uint2 v0 = *(const uint2*)&t8[(size_t)s0 * 128 + l * 8];
        uint2 v1 = *(const uint2*)&t8[(size_t)s1 * 128 + l * 8];
        ACCA(v0) ACCB(v1)
    }
    if (i < end) {
        int s0 = sortedSrc[i];
        uint2 v0 = *(const uint2*)&t8[(size_t)s0 * 128 + l * 8];
        ACCA(v0)
    }
#undef ACCA
#undef ACCB
    a0 += b0; a1 += b1; a2 += b2; a3 += b3;
    a4 += b4; a5 += b5; a6 += b6; a7 += b7;
#define CMB(a) a += __shfl_xor(a, 32); a += __shfl_xor(a, 16);
    CMB(a0) CMB(a1) CMB(a2) CMB(a3) CMB(a4) CMB(a5) CMB(a6) CMB(a7)
#undef CMB
    if (lane < 16) {
        float id = 1.0f / fmaxf((float)(end - beg), 1.0f);
        ushort p[8];
        p[0] = f2bf(a0 * id); p[1] = f2bf(a1 * id);
        p[2] = f2bf(a2 * id); p[3] = f2bf(a3 * id);
        p[4] = f2bf(a4 * id); p[5] = f2bf(a5 * id);
        p[6] = f2bf(a6 * id); p[7] = f2bf(a7 * id);
        *(uint4*)&mean[(size_t)node * 128 + l * 8] = *(uint4*)p;
    }
}

// ---------------- weight prep ----------------
__global__ __launch_bounds__(256) void prep_w(const float* __restrict__ W1l,
                                              const float* __restrict__ W1r,
                                              const float* __restrict__ Wlin,
                                              const float* __restrict__ W2l,
                                              const float* __restrict__ W2r,
                                              ushort* __restrict__ Wcat1,
                                              ushort* __restrict__ Wlinb,
                                              ushort* __restrict__ Wcat2) {
    int i = blockIdx.x * 256 + threadIdx.x;
    if (i < 65536) {
        int o = i >> 8, k = i & 255;
        float v = (k < 128) ? W1l[o * 128 + k] : W1r[o * 128 + k - 128];
        Wcat1[i] = f2bf(v);
    } else if (i < 98304) {
        int j = i - 65536;
        Wlinb[j] = f2bf(Wlin[j]);
    } else {
        int j = i - 98304;
        int o = j >> 8, k = j & 255;
        float v = (k < 128) ? W2l[o * 128 + k] : W2r[o * 128 + k - 128];
        Wcat2[j] = f2bf(v);
    }
}

// ---------------- x fp32 -> bf16 + fp8 ----------------
__global__ __launch_bounds__(256) void xcvt(const float* __restrict__ x,
                                            ushort* __restrict__ xbf,
                                            uchar* __restrict__ x8) {
    int i = blockIdx.x * 256 + threadIdx.x;   // over NN*128/4
    float4 v = ((const float4*)x)[i];
    ushort4 p;
    p.x = f2bf(v.x); p.y = f2bf(v.y); p.z = f2bf(v.z); p.w = f2bf(v.w);
    ((ushort4*)xbf)[i] = p;
    uint q = f2fp8(v.x) | (f2fp8(v.y) << 8) | (f2fp8(v.z) << 16) | (f2fp8(v.w) << 24);
    ((uint*)x8)[i] = q;
}

// ---------------- hr bf16 -> fp8 ----------------
__global__ __launch_bounds__(256) void cvt8(const ushort* __restrict__ hr,
                                            uchar* __restrict__ hr8) {
    int i = blockIdx.x * 256 + threadIdx.x;   // over NN*128/8
    uint4 v = ((const uint4*)hr)[i];
    uint lo = f2fp8(bf2f(v.x & 0xffffu)) | (f2fp8(bf2f(v.x >> 16)) << 8) |
              (f2fp8(bf2f(v.y & 0xffffu)) << 16) | (f2fp8(bf2f(v.y >> 16)) << 24);
    uint hi = f2fp8(bf2f(v.z & 0xffffu)) | (f2fp8(bf2f(v.z >> 16)) << 8) |
              (f2fp8(bf2f(v.w & 0xffffu)) << 16) | (f2fp8(bf2f(v.w >> 16)) << 24);
    uint2 o; o.x = lo; o.y = hi;
    ((uint2*)hr8)[i] = o;
}

// --- conv1+linear fused: h = l2norm([mean|x]@Wcat1^T + b1), hr = relu(h@Wlin^T + blin)
__global__ __launch_bounds__(256) void conv1lin_mfma(const ushort* __restrict__ mean,
                                                     const ushort* __restrict__ xbf,
                                                     const ushort* __restrict__ Wcat,
                                                     const float* __restrict__ bias1,
                                                     const ushort* __restrict__ Wlin,
                                                     const float* __restrict__ blin,
                                                     ushort* __restrict__ hr) {
    __shared__ char As[64 * 512];
    __shared__ char Bs[64 * 512];
    int m0 = blockIdx.x * 64;
    int tid = threadIdx.x;
    for (int c = tid; c < 2048; c += 256) {
        int m = c >> 5, kc = c & 31;
        int mm = min(m0 + m, NN - 1);
        uint4 v = (kc < 16) ? *(const uint4*)&mean[(size_t)mm * 128 + kc * 8]
                            : *(const uint4*)&xbf[(size_t)mm * 128 + (kc - 16) * 8];
        *(uint4*)(As + swz(m * 512 + kc * 16)) = v;
    }
    for (int j = tid; j < 2048; j += 256)
        *(uint4*)(Bs + swz((j >> 5) * 512 + (j & 31) * 16)) = *(const uint4*)&Wcat[j * 8];
    __syncthreads();

    int lane = tid & 63, wave = tid >> 6;
    int col = lane & 15, kg = lane >> 4;
    int mym = wave * 16 + col;
    short8 a[8];
#pragma unroll
    for (int ks = 0; ks < 8; ++ks)
        a[ks] = *(const short8*)(As + swz(mym * 512 + (ks * 32 + kg * 8) * 2));
    f32x4 acc[16];
#pragma unroll
    for (int nt = 0; nt < 4; ++nt) {
        f32x4 c = {0.f, 0.f, 0.f, 0.f};
#pragma unroll
        for (int ks = 0; ks < 8; ++ks)
            c = __builtin_amdgcn_mfma_f32_16x16x32_bf16(
                a[ks], *(const short8*)(Bs + swz((nt * 16 + col) * 512 + (ks * 32 + kg * 8) * 2)), c, 0, 0, 0);
        acc[nt] = c;
    }
    for (int ch = 1; ch < 4; ++ch) {
        __syncthreads();
        for (int j = tid; j < 2048; j += 256)
            *(uint4*)(Bs + swz((j >> 5) * 512 + (j & 31) * 16)) =
                *(const uint4*)&Wcat[ch * 16384 + j * 8];
        __syncthreads();
#pragma unroll
        for (int nt = 0; nt < 4; ++nt) {
            f32x4 c = {0.f, 0.f, 0.f, 0.f};
#pragma unroll
            for (int ks = 0; ks < 8; ++ks)
                c = __builtin_amdgcn_mfma_f32_16x16x32_bf16(
                    a[ks], *(const short8*)(Bs + swz((nt * 16 + col) * 512 + (ks * 32 + kg * 8) * 2)), c, 0, 0, 0);
            acc[ch * 4 + nt] = c;
        }
    }
    // bias + l2norm
    float ssq[4] = {0.f, 0.f, 0.f, 0.f};
#pragma unroll
    for (int nt = 0; nt < 16; ++nt) {
        float b = bias1[nt * 16 + col];
#pragma unroll
        for (int r = 0; r < 4; ++r) {
            acc[nt][r] += b;
            ssq[r] += acc[nt][r] * acc[nt][r];
        }
    }
#pragma unroll
    for (int off = 1; off < 16; off <<= 1)
#pragma unroll
        for (int r = 0; r < 4; ++r) ssq[r] += __shfl_xor(ssq[r], off);
    float rn[4];
#pragma unroll
    for (int r = 0; r < 4; ++r) rn[r] = 1.0f / fmaxf(sqrtf(ssq[r]), 1e-12f);
    // write h (bf16) into As
#pragma unroll
    for (int r = 0; r < 4; ++r) {
        int rl = wave * 16 + kg * 4 + r;
#pragma unroll
        for (int nt = 0; nt < 16; ++nt)
            *(ushort*)(As + swz(rl * 512 + (nt * 16 + col) * 2)) = f2bf(acc[nt][r] * rn[r]);
    }
    __syncthreads();
    // second GEMM: hr = relu(h @ Wlin^T + blin)
    short8 a2[8];
#pragma unroll
    for (int ks = 0; ks < 8; ++ks)
        a2[ks] = *(const short8*)(As + swz(mym * 512 + (ks * 32 + kg * 8) * 2));
    for (int j = tid; j < 2048; j += 256)
        *(uint4*)(Bs + swz((j >> 5) * 512 + (j & 31) * 16)) = *(const uint4*)&Wlin[j * 8];
    __syncthreads();
    f32x4 acc2[8];
#pragma unroll
    for (int nt = 0; nt < 4; ++nt) {
        f32x4 c = {0.f, 0.f, 0.f, 0.f};
#pragma unroll
        for (int ks = 0; ks < 8; ++ks)
            c = __builtin_amdgcn_mfma_f32_16x16x32_bf16(
                a2[ks], *(const short8*)(Bs + swz((nt * 16 + col) * 512 + (ks * 32 + kg * 8) * 2)), c, 0, 0, 0);
        acc2[nt] = c;
    }
    __syncthreads();
    for (int j = tid; j < 2048; j += 256)
        *(uint4*)(Bs + swz((j >> 5) * 512 + (j & 31) * 16)) = *(const uint4*)&Wlin[16384 + j * 8];
    __syncthreads();
#pragma unroll
    for (int nt = 0; nt < 4; ++nt) {
        f32x4 c = {0.f, 0.f, 0.f, 0.f};
#pragma unroll
        for (int ks = 0; ks < 8; ++ks)
            c = __builtin_amdgcn_mfma_f32_16x16x32_bf16(
                a2[ks], *(const short8*)(Bs + swz((nt * 16 + col) * 512 + (ks * 32 + kg * 8) * 2)), c, 0, 0, 0);
        acc2[4 + nt] = c;
    }
#pragma unroll
    for (int r = 0; r < 4; ++r) {
        int node = m0 + wave * 16 + kg * 4 + r;
        if (node < NN) {
#pragma unroll
            for (int nt = 0; nt < 8; ++nt) {
                float vv = acc2[nt][r] + blin[nt * 16 + col];
                hr[(size_t)node * 128 + nt * 16 + col] = f2bf(fmaxf(vv, 0.f));
            }
        }
    }
}

// ------- conv2 + linear2 + softmax -------
__global__ __launch_bounds__(256) void conv2_mfma(const ushort* __restrict__ mean,
                                                  const ushort* __restrict__ hr,
                                                  const ushort* __restrict__ Wcat,
                                                  const float* __restrict__ bias,
                                                  const float* __restrict__ Wlin2,
                                                  const float* __restrict__ blin2,
                                                  float* __restrict__ probs,
                                                  float* __restrict__ yout) {
    __shared__ char As[64 * 512];
    __shared__ char Bs[64 * 512];
    int m0 = blockIdx.x * 64;
    int tid = threadIdx.x;
    for (int c = tid; c < 2048; c += 256) {
        int m = c >> 5, kc = c & 31;
        int mm = min(m0 + m, NN - 1);
        uint4 v = (kc < 16) ? *(const uint4*)&mean[(size_t)mm * 128 + kc * 8]
                            : *(const uint4*)&hr[(size_t)mm * 128 + (kc - 16) * 8];
        *(uint4*)(As + swz(m * 512 + kc * 16)) = v;
    }
    for (int j = tid; j < 2048; j += 256)
        *(uint4*)(Bs + swz((j >> 5) * 512 + (j & 31) * 16)) = *(const uint4*)&Wcat[j * 8];
    __syncthreads();

    int lane = tid & 63, wave = tid >> 6;
    int col = lane & 15, kg = lane >> 4;
    int mym = wave * 16 + col;
    short8 a[8];
#pragma unroll
    for (int ks = 0; ks < 8; ++ks)
        a[ks] = *(const short8*)(As + swz(mym * 512 + (ks * 32 + kg * 8) * 2));
    f32x4 acc[8];
#pragma unroll
    for (int nt = 0; nt < 4; ++nt) {
        f32x4 c = {0.f, 0.f, 0.f, 0.f};
#pragma unroll
        for (int ks = 0; ks < 8; ++ks)
            c = __builtin_amdgcn_mfma_f32_16x16x32_bf16(
                a[ks], *(const short8*)(Bs + swz((nt * 16 + col) * 512 + (ks * 32 + kg * 8) * 2)), c, 0, 0, 0);
        acc[nt] = c;
    }
    __syncthreads();
    for (int j = tid; j < 2048; j += 256)
        *(uint4*)(Bs + swz((j >> 5) * 512 + (j & 31) * 16)) = *(const uint4*)&Wcat[16384 + j * 8];
    __syncthreads();
#pragma unroll
    for (int nt = 0; nt < 4; ++nt) {
        f32x4 c = {0.f, 0.f, 0.f, 0.f};
#pragma unroll
        for (int ks = 0; ks < 8; ++ks)
            c = __builtin_amdgcn_mfma_f32_16x16x32_bf16(
                a[ks], *(const short8*)(Bs + swz((nt * 16 + col) * 512 + (ks * 32 + kg * 8) * 2)), c, 0, 0, 0);
        acc[4 + nt] = c;
    }
    float ssq[4] = {0.f, 0.f, 0.f, 0.f};
#pragma unroll
    for (int nt = 0; nt < 8; ++nt) {
        float b = bias[nt * 16 + col];
#pragma unroll
        for (int r = 0; r < 4; ++r) {
            acc[nt][r] += b;
            ssq[r] += acc[nt][r] * acc[nt][r];
        }
    }
#pragma unroll
    for (int off = 1; off < 16; off <<= 1)
#pragma unroll
        for (int r = 0; r < 4; ++r) ssq[r] += __shfl_xor(ssq[r], off);
    float rn[4], p0[4] = {0.f,0.f,0.f,0.f}, p1[4] = {0.f,0.f,0.f,0.f};
#pragma unroll
    for (int r = 0; r < 4; ++r) rn[r] = 1.0f / fmaxf(sqrtf(ssq[r]), 1e-12f);
#pragma unroll
    for (int nt = 0; nt < 8; ++nt) {
        float w0 = Wlin2[nt * 16 + col], w1 = Wlin2[128 + nt * 16 + col];
#pragma unroll
        for (int r = 0; r < 4; ++r) {
            float yv = acc[nt][r] * rn[r];
            acc[nt][r] = yv;
            p0[r] += yv * w0;
            p1[r] += yv * w1;
        }
    }
#pragma unroll
    for (int off = 1; off < 16; off <<= 1)
#pragma unroll
        for (int r = 0; r < 4; ++r) { p0[r] += __shfl_xor(p0[r], off); p1[r] += __shfl_xor(p1[r], off); }
#pragma unroll
    for (int r = 0; r < 4; ++r) {
        int node = m0 + wave * 16 + kg * 4 + r;
        if (node < NN) {
#pragma unroll
            for (int nt = 0; nt < 8; ++nt)
                yout[(size_t)node * 128 + nt * 16 + col] = acc[nt][r];
            if (col == 0) {
                float l0 = p0[r] + blin2[0], l1 = p1[r] + blin2[1];
                float mx = fmaxf(l0, l1);
                float e0 = expf(l0 - mx), e1 = expf(l1 - mx);
                float inv = 1.0f / (e0 + e1);
                probs[(size_t)node * 2 + 0] = e0 * inv;
                probs[(size_t)node * 2 + 1] = e1 * inv;
            }
        }
    }
}

extern "C" void kernel_launch(void* const* d_in, const int* in_sizes, int n_in,
                              void* d_out, int out_size, void* d_ws, size_t ws_size,
                              hipStream_t stream) {
    const float* x     = (const float*)d_in[0];
    const int*   ei    = (const int*)d_in[1];
    const int*   src   = ei;
    const int*   tgt   = ei + NE;
    const float* W1l   = (const float*)d_in[2];
    const float* b1l   = (const float*)d_in[3];
    const float* W1r   = (const float*)d_in[4];
    const float* Wlin  = (const float*)d_in[5];
    const float* blin  = (const float*)d_in[6];
    const float* W2l   = (const float*)d_in[7];
    const float* b2l   = (const float*)d_in[8];
    const float* W2r   = (const float*)d_in[9];
    const float* Wlin2 = (const float*)d_in[10];
    const float* blin2 = (const float*)d_in[11];

    float* probs = (float*)d_out;              // [N,2]
    float* y     = (float*)d_out + 2 * NN;     // [N,128]

    // ws layout
    int*    bcnt      = (int*)d_ws;                     // NBK
    int*    bbase     = bcnt + NBK;                     // NBK+1
    int*    bcursor   = bbase + NBK + 1;                // NBK
    int*    rowstart  = bcursor + NBK;                  // NN+1
    uint*   brec      = (uint*)(rowstart + NN + 1);     // NE
    int*    sortedSrc = (int*)(brec + NE);              // NE
    ushort* Wcat1     = (ushort*)(sortedSrc + NE);      // 256*256
    ushort* Wlinb     = Wcat1 + 65536;                  // 128*256
    ushort* Wcat2     = Wlinb + 32768;                  // 128*256
    ushort* xbf       = Wcat2 + 32768;                  // N*128 bf16
    ushort* hr        = xbf + (size_t)NN * 128;         // N*128 bf16
    ushort* mean      = hr + (size_t)NN * 128;          // N*128 bf16
    uchar*  x8        = (uchar*)(mean + (size_t)NN * 128); // N*128 fp8
    uchar*  hr8       = x8 + (size_t)NN * 128;          // N*128 fp8

    const int NEB = (NE + EPB - 1) / EPB;               // 196 edge blocks

    hipMemsetAsync(bcnt, 0, sizeof(int) * NBK, stream);

    prep_w<<<512, 256, 0, stream>>>(W1l, W1r, Wlin, W2l, W2r, Wcat1, Wlinb, Wcat2);
    xcvt<<<NN * 32 / 256, 256, 0, stream>>>(x, xbf, x8);

    bucket_hist<<<NEB, 256, 0, stream>>>(tgt, bcnt);
    bucket_scan<<<1, 256, 0, stream>>>(bcnt, bbase, bcursor, rowstart);
    bucket_scatter<<<NEB, 256, 0, stream>>>(src, tgt, bcursor, brec);
    bucket_to_csr<<<NBK, 256, 0, stream>>>(brec, bbase, rowstart, sortedSrc);

    gather_mean8<<<(NN + 3) / 4, 256, 0, stream>>>(x8, rowstart, sortedSrc, mean);
    conv1lin_mfma<<<(NN + 63) / 64, 256, 0, stream>>>(mean, xbf, Wcat1, b1l,
                                                      Wlinb, blin, hr);
    cvt8<<<NN * 128 / 8 / 256, 256, 0, stream>>>(hr, hr8);
    gather_mean8<<<(NN + 3) / 4, 256, 0, stream>>>(hr8, rowstart, sortedSrc, mean);
    conv2_mfma<<<(NN + 63) / 64, 256, 0, stream>>>(mean, hr, Wcat2, b2l,
                                                   Wlin2, blin2, probs, y);
}